// Round 18
// baseline (432.450 us; speedup 1.0000x reference)
//
#include <hip/hip_runtime.h>
#include <hip/hip_bf16.h>

typedef float f32x4 __attribute__((ext_vector_type(4)));
typedef __bf16 bf16x8 __attribute__((ext_vector_type(8)));
typedef unsigned short us8 __attribute__((ext_vector_type(8)));

#define MBYTE (1ull << 20)

#define QSCALE_LOG2E 0.18033688011112042f
#define GELU_K 2.3022081902f

__device__ __forceinline__ unsigned short f2bf(float f) {
    __bf16 h = (__bf16)f;
    return __builtin_bit_cast(unsigned short, h);
}

__device__ __forceinline__ float fast_exp2(float x) {
    return __builtin_amdgcn_exp2f(x);
}

__device__ __forceinline__ f32x4 mfma16(bf16x8 a, bf16x8 b, f32x4 c) {
    return __builtin_amdgcn_mfma_f32_16x16x32_bf16(a, b, c, 0, 0, 0);
}

__device__ __forceinline__ void gload16(const void* g, void* l) {
    __builtin_amdgcn_global_load_lds(
        (const __attribute__((address_space(1))) unsigned int*)g,
        (__attribute__((address_space(3))) unsigned int*)l, 16, 0, 0);
}

// ---------------- LayerNorm: fp32 [rows][1024] -> bf16 ----------------
__global__ __launch_bounds__(256) void ln_kernel(const float* __restrict__ x,
                                                 unsigned short* __restrict__ out) {
    int row = blockIdx.x;
    int t = threadIdx.x;
    const float* xr = x + (size_t)row * 1024;
    float4 v = *(const float4*)(xr + t * 4);
    float s = v.x + v.y + v.z + v.w;
    float ss = v.x * v.x + v.y * v.y + v.z * v.z + v.w * v.w;
    #pragma unroll
    for (int off = 1; off < 64; off <<= 1) {
        s += __shfl_xor(s, off);
        ss += __shfl_xor(ss, off);
    }
    __shared__ float ps[4], pss[4];
    int wid = t >> 6, lane = t & 63;
    if (lane == 0) { ps[wid] = s; pss[wid] = ss; }
    __syncthreads();
    s = ps[0] + ps[1] + ps[2] + ps[3];
    ss = pss[0] + pss[1] + pss[2] + pss[3];
    float mean = s * (1.0f / 1024.0f);
    float var = ss * (1.0f / 1024.0f) - mean * mean;
    float rs = rsqrtf(var + 1e-6f);
    ushort4 ov;
    ov.x = f2bf((v.x - mean) * rs);
    ov.y = f2bf((v.y - mean) * rs);
    ov.z = f2bf((v.z - mean) * rs);
    ov.w = f2bf((v.w - mean) * rs);
    *(ushort4*)(out + (size_t)row * 1024 + t * 4) = ov;
}

// ------------- transpose + fp32->bf16: W[K][N] -> Wt[N][K] -------------
__global__ __launch_bounds__(256) void convT_kernel(const float* __restrict__ W,
                                                    unsigned short* __restrict__ Wt,
                                                    int K, int N) {
    __shared__ float tile[32][33];
    int t = threadIdx.x;
    int tx = t & 31, ty = t >> 5;
    int bx = blockIdx.x, by = blockIdx.y;
    #pragma unroll
    for (int r = 0; r < 4; r++) {
        int row = by * 32 + ty + r * 8;
        int col = bx * 32 + tx;
        tile[ty + r * 8][tx] = W[(size_t)row * N + col];
    }
    __syncthreads();
    #pragma unroll
    for (int r = 0; r < 4; r++) {
        int orow = bx * 32 + ty + r * 8;
        int ocol = by * 32 + tx;
        Wt[(size_t)orow * K + ocol] = f2bf(tile[tx][ty + r * 8]);
    }
}

// ------------- V transpose: qkv V-part bf16 -> vT[bh][64][2048] -------------
__global__ __launch_bounds__(256) void vT_kernel(const unsigned short* __restrict__ qkv,
                                                 unsigned short* __restrict__ vT) {
    __shared__ unsigned short tile[32][34];
    int t = threadIdx.x;
    int tx = t & 31, ty = t >> 5;
    int lt = blockIdx.x, dt = blockIdx.y, bh = blockIdx.z;
    int b = bh >> 4, h = bh & 15;
    const unsigned short* src = qkv + (size_t)(b * 2048 + lt * 32) * 3072 + 2048 + h * 64 + dt * 32;
    #pragma unroll
    for (int r = 0; r < 4; r++)
        tile[ty + r * 8][tx] = src[(size_t)(ty + r * 8) * 3072 + tx];
    __syncthreads();
    int perm = (lt & 1) * 32 + ((tx >> 2) & 3) * 8 + ((tx >> 4) & 1) * 4 + (tx & 3);
    unsigned short* dst = vT + ((size_t)bh * 64 + dt * 32) * 2048 + (size_t)(lt >> 1) * 64;
    #pragma unroll
    for (int r = 0; r < 4; r++)
        dst[(size_t)(ty + r * 8) * 2048 + perm] = tile[tx][ty + r * 8];
}

// ------- GEMM v9 (R17-proven): 256xBN tile, BK=64, 8 waves, 4-phase quadrant
// schedule, counted end-of-tile vmcnt, region-safe late staging. ------
template <int EPI, int BN>
__global__ __launch_bounds__(512, 2) void gemm8p(const unsigned short* __restrict__ A,
                                                 const unsigned short* __restrict__ Bt,
                                                 const float* __restrict__ bias,
                                                 const float* __restrict__ res,
                                                 float* __restrict__ outF,
                                                 unsigned short* __restrict__ outB,
                                                 int M, int N, int K) {
    constexpr int NREP = BN / 64;
    constexpr int NH = NREP / 2;
    constexpr int BHROWS = BN / 2;
    constexpr int WCOLS = BN / 4;

    __shared__ __align__(16) unsigned short As[2][2][128 * 64];
    __shared__ __align__(16) unsigned short Bs[2][2][BHROWS * 64];

    int t = threadIdx.x;
    int lane = t & 63, wid = t >> 6;
    int ql = lane & 15, hi = lane >> 4;

    // XCD-aware bijective swizzle (grids: 768/256/1024/256, all %8==0)
    int gx = gridDim.x;
    int nwg = gx * gridDim.y;
    int orig = blockIdx.y * gx + blockIdx.x;
    int cpx = nwg >> 3;
    int swz = (orig & 7) * cpx + (orig >> 3);
    int bm = swz / gx, bn = swz % gx;

    int wm = wid >> 2, wn = wid & 3;
    f32x4 acc[8][NREP] = {};

    int lrow = lane >> 3;
    int schunk = ((lane & 7) ^ lrow) * 8;
    const unsigned short* gA = A + (size_t)(bm * 256 + wid * 8 + lrow) * K + schunk;
    const unsigned short* gB = Bt + (size_t)(bn * BN + wid * 8 + lrow) * K + schunk;

    auto SA = [&](int d, int hh, int kt) {
        size_t ko = (size_t)kt * 64;
        gload16(gA + (size_t)(hh * 128) * K + ko, &As[d][hh][(wid * 8) * 64]);
        gload16(gA + (size_t)(hh * 128 + 64) * K + ko, &As[d][hh][(64 + wid * 8) * 64]);
    };
    auto SB = [&](int d, int hh, int kt) {
        size_t ko = (size_t)kt * 64;
        gload16(gB + (size_t)(hh * BHROWS) * K + ko, &Bs[d][hh][(wid * 8) * 64]);
        if constexpr (BN == 256)
            gload16(gB + (size_t)(hh * BHROWS + 64) * K + ko, &Bs[d][hh][(64 + wid * 8) * 64]);
    };

    int rsl0 = ((0 + hi) ^ (ql & 7)) * 8;
    int rsl1 = ((4 + hi) ^ (ql & 7)) * 8;

    const int NT = K >> 6;
    int bh_ = (WCOLS * wn) / BHROWS;
    int brow = (WCOLS * wn) % BHROWS;

    auto GATE_N = [&]() {
        if constexpr (BN == 256) asm volatile("s_waitcnt vmcnt(8)" ::: "memory");
        else                     asm volatile("s_waitcnt vmcnt(6)" ::: "memory");
    };

    SA(0, 0, 0); SA(0, 1, 0); SB(0, 0, 0); SB(0, 1, 0);
    __builtin_amdgcn_sched_barrier(0);
    SA(1, 0, 1); SA(1, 1, 1); SB(1, 0, 1); SB(1, 1, 1);
    GATE_N();
    __builtin_amdgcn_sched_barrier(0);
    __builtin_amdgcn_s_barrier();

    for (int kt = 0; kt < NT; ++kt) {
        int d = kt & 1;
        bool st = (kt + 2 < NT);
        const unsigned short* Ah = &As[d][wm][0];
        const unsigned short* Bh = &Bs[d][bh_][0];

        bf16x8 af[4][2], bfa[NH][2], bfb[NH][2];

        // ---- ph0 ----
        #pragma unroll
        for (int m = 0; m < 4; m++) {
            af[m][0] = *(const bf16x8*)&Ah[(m * 16 + ql) * 64 + rsl0];
            af[m][1] = *(const bf16x8*)&Ah[(m * 16 + ql) * 64 + rsl1];
        }
        #pragma unroll
        for (int n = 0; n < NH; n++) {
            bfa[n][0] = *(const bf16x8*)&Bh[(brow + n * 16 + ql) * 64 + rsl0];
            bfa[n][1] = *(const bf16x8*)&Bh[(brow + n * 16 + ql) * 64 + rsl1];
        }
        __builtin_amdgcn_s_setprio(1);
        #pragma unroll
        for (int m = 0; m < 4; m++)
            #pragma unroll
            for (int n = 0; n < NH; n++) {
                acc[m][n] = mfma16(af[m][0], bfa[n][0], acc[m][n]);
                acc[m][n] = mfma16(af[m][1], bfa[n][1], acc[m][n]);
            }
        __builtin_amdgcn_s_setprio(0);

        // ---- ph1 ----
        #pragma unroll
        for (int n = 0; n < NH; n++) {
            bfb[n][0] = *(const bf16x8*)&Bh[(brow + NH * 16 + n * 16 + ql) * 64 + rsl0];
            bfb[n][1] = *(const bf16x8*)&Bh[(brow + NH * 16 + n * 16 + ql) * 64 + rsl1];
        }
        __builtin_amdgcn_s_setprio(1);
        #pragma unroll
        for (int m = 0; m < 4; m++)
            #pragma unroll
            for (int n = 0; n < NH; n++) {
                acc[m][NH + n] = mfma16(af[m][0], bfb[n][0], acc[m][NH + n]);
                acc[m][NH + n] = mfma16(af[m][1], bfb[n][1], acc[m][NH + n]);
            }
        __builtin_amdgcn_s_setprio(0);

        if (st) {
            asm volatile("s_waitcnt lgkmcnt(0)" ::: "memory");
            __builtin_amdgcn_sched_barrier(0);
            __builtin_amdgcn_s_barrier();
        }

        // ---- ph2 ----
        if (st) { SB(d, 0, kt + 2); SB(d, 1, kt + 2); }
        #pragma unroll
        for (int m = 0; m < 4; m++) {
            af[m][0] = *(const bf16x8*)&Ah[(64 + m * 16 + ql) * 64 + rsl0];
            af[m][1] = *(const bf16x8*)&Ah[(64 + m * 16 + ql) * 64 + rsl1];
        }
        __builtin_amdgcn_s_setprio(1);
        #pragma unroll
        for (int m = 0; m < 4; m++)
            #pragma unroll
            for (int n = 0; n < NH; n++) {
                acc[4 + m][n] = mfma16(af[m][0], bfa[n][0], acc[4 + m][n]);
                acc[4 + m][n] = mfma16(af[m][1], bfa[n][1], acc[4 + m][n]);
            }
        __builtin_amdgcn_s_setprio(0);

        if (st) {
            asm volatile("s_waitcnt lgkmcnt(0)" ::: "memory");
            __builtin_amdgcn_sched_barrier(0);
            __builtin_amdgcn_s_barrier();
        }

        // ---- ph3 ----
        if (st) { SA(d, 0, kt + 2); SA(d, 1, kt + 2); }
        __builtin_amdgcn_s_setprio(1);
        #pragma unroll
        for (int m = 0; m < 4; m++)
            #pragma unroll
            for (int n = 0; n < NH; n++) {
                acc[4 + m][NH + n] = mfma16(af[m][0], bfb[n][0], acc[4 + m][NH + n]);
                acc[4 + m][NH + n] = mfma16(af[m][1], bfb[n][1], acc[4 + m][NH + n]);
            }
        __builtin_amdgcn_s_setprio(0);

        if (st) GATE_N();
        else    asm volatile("s_waitcnt vmcnt(0)" ::: "memory");
        __builtin_amdgcn_sched_barrier(0);
        __builtin_amdgcn_s_barrier();
    }

    #pragma unroll
    for (int m = 0; m < 8; m++) {
        #pragma unroll
        for (int n = 0; n < NREP; n++) {
            int col = bn * BN + wn * WCOLS + n * 16 + ql;
            float bv = bias[col];
            #pragma unroll
            for (int r = 0; r < 4; r++) {
                int row = bm * 256 + wm * 128 + m * 16 + hi * 4 + r;
                float val = acc[m][n][r] + bv;
                if (EPI == 0) {
                    if (col < 1024) val *= QSCALE_LOG2E;
                    outB[(size_t)row * N + col] = f2bf(val);
                } else if (EPI == 1) {
                    float w = val + 0.044715f * val * val * val;
                    float g = val / (1.0f + fast_exp2(-GELU_K * w));
                    outB[(size_t)row * N + col] = f2bf(g);
                } else {
                    outF[(size_t)row * N + col] = val + res[(size_t)row * N + col];
                }
            }
        }
    }
}

// --- Flash attention v9 (R14-proven): swapped QK^T, in-register P, no max
//     tracking, lsum via ones-MFMA, dbuf stage-before-compute, 1 barrier/tile ---
__global__ __launch_bounds__(256) void attn_kernel(const unsigned short* __restrict__ qkv,
                                                   const unsigned short* __restrict__ vT,
                                                   unsigned short* __restrict__ o) {
    int bid = blockIdx.x;
    int qb = bid & 31;
    int bh = bid >> 5;
    int b = bh >> 4, h = bh & 15;
    int t = threadIdx.x, lane = t & 63, wid = t >> 6;

    const unsigned short* base = qkv + (size_t)b * 2048 * 3072 + h * 64;
    const unsigned short* vbase = vT + (size_t)bh * 64 * 2048;

    __shared__ __align__(16) unsigned short Ks[2][2][64][32];
    __shared__ __align__(16) unsigned short Vs[2][2][64][32];

    int ql = lane & 15;
    int hi = lane >> 4;

    bf16x8 qf[2];
    {
        int qrow = qb * 64 + wid * 16 + ql;
        const unsigned short* qp = base + (size_t)qrow * 3072 + hi * 8;
        qf[0] = *(const bf16x8*)(qp);
        qf[1] = *(const bf16x8*)(qp + 32);
    }

    us8 ones_u;
    #pragma unroll
    for (int j = 0; j < 8; j++) ones_u[j] = 0x3F80;
    bf16x8 ones = __builtin_bit_cast(bf16x8, ones_u);

    f32x4 accO[4] = {};
    f32x4 lacc = {};

    int srow = wid * 16 + (lane >> 2);
    int schunk = ((lane & 3) ^ ((lane >> 3) & 3)) * 8;
    const unsigned short* gk = base + 1024 + (size_t)srow * 3072 + schunk;
    const unsigned short* gv = vbase + (size_t)srow * 2048 + schunk;

    auto STAGE = [&](int buf, int kt) {
        const unsigned short* pk = gk + (size_t)kt * 64 * 3072;
        const unsigned short* pv = gv + (size_t)kt * 64;
        gload16(pk, &Ks[buf][0][wid * 16][0]);
        gload16(pk + 32, &Ks[buf][1][wid * 16][0]);
        gload16(pv, &Vs[buf][0][wid * 16][0]);
        gload16(pv + 32, &Vs[buf][1][wid * 16][0]);
    };

    int rchunk = (hi ^ ((ql >> 1) & 3)) * 8;

    STAGE(0, 0);
    asm volatile("s_waitcnt vmcnt(0)" ::: "memory");
    __builtin_amdgcn_sched_barrier(0);
    __builtin_amdgcn_s_barrier();

    int buf = 0;
    for (int kt = 0; kt < 32; kt++) {
        if (kt + 1 < 32) STAGE(buf ^ 1, kt + 1);

        f32x4 s0 = {}, s1 = {}, s2 = {}, s3 = {};
        #pragma unroll
        for (int c = 0; c < 2; c++) {
            bf16x8 a0 = *(const bf16x8*)&Ks[buf][c][ 0 + ql][rchunk];
            bf16x8 a1 = *(const bf16x8*)&Ks[buf][c][16 + ql][rchunk];
            bf16x8 a2 = *(const bf16x8*)&Ks[buf][c][32 + ql][rchunk];
            bf16x8 a3 = *(const bf16x8*)&Ks[buf][c][48 + ql][rchunk];
            s0 = mfma16(a0, qf[c], s0);
            s1 = mfma16(a1, qf[c], s1);
            s2 = mfma16(a2, qf[c], s2);
            s3 = mfma16(a3, qf[c], s3);
        }

        us8 pu0, pu1;
        #pragma unroll
        for (int j = 0; j < 4; j++) {
            pu0[j]     = f2bf(fast_exp2(s0[j]));
            pu0[4 + j] = f2bf(fast_exp2(s1[j]));
            pu1[j]     = f2bf(fast_exp2(s2[j]));
            pu1[4 + j] = f2bf(fast_exp2(s3[j]));
        }
        bf16x8 paf0 = __builtin_bit_cast(bf16x8, pu0);
        bf16x8 paf1 = __builtin_bit_cast(bf16x8, pu1);

        #pragma unroll
        for (int nn = 0; nn < 4; nn++) {
            bf16x8 bv0 = *(const bf16x8*)&Vs[buf][0][nn * 16 + ql][rchunk];
            bf16x8 bv1 = *(const bf16x8*)&Vs[buf][1][nn * 16 + ql][rchunk];
            accO[nn] = mfma16(paf0, bv0, accO[nn]);
            accO[nn] = mfma16(paf1, bv1, accO[nn]);
        }
        lacc = mfma16(paf0, ones, lacc);
        lacc = mfma16(paf1, ones, lacc);

        asm volatile("s_waitcnt vmcnt(0)" ::: "memory");
        __builtin_amdgcn_sched_barrier(0);
        __builtin_amdgcn_s_barrier();
        buf ^= 1;
    }

    #pragma unroll
    for (int r = 0; r < 4; r++) {
        float rq = 1.0f / lacc[r];
        int row = qb * 64 + wid * 16 + hi * 4 + r;
        #pragma unroll
        for (int nn = 0; nn < 4; nn++) {
            int col = h * 64 + nn * 16 + ql;
            o[(size_t)(b * 2048 + row) * 1024 + col] = f2bf(accO[nn][r] * rq);
        }
    }
}

extern "C" void kernel_launch(void* const* d_in, const int* in_sizes, int n_in,
                              void* d_out, int out_size, void* d_ws, size_t ws_size,
                              hipStream_t stream) {
    const float* x      = (const float*)d_in[0];
    const float* qkv_w  = (const float*)d_in[1];
    const float* qkv_b  = (const float*)d_in[2];
    const float* proj_w = (const float*)d_in[3];
    const float* proj_b = (const float*)d_in[4];
    const float* fc1_w  = (const float*)d_in[5];
    const float* fc1_b  = (const float*)d_in[6];
    const float* fc2_w  = (const float*)d_in[7];
    const float* fc2_b  = (const float*)d_in[8];
    float* out = (float*)d_out;

    char* ws = (char*)d_ws;
    unsigned short* h_buf   = (unsigned short*)(ws + 0 * MBYTE);
    unsigned short* qkv_buf = (unsigned short*)(ws + 16 * MBYTE);
    unsigned short* o_buf   = (unsigned short*)(ws + 64 * MBYTE);
    float*          x2_buf  = (float*)(ws + 80 * MBYTE);
    unsigned short* vT_buf  = (unsigned short*)(ws + 80 * MBYTE);
    unsigned short* wqT     = (unsigned short*)(ws + 112 * MBYTE);
    unsigned short* wpT     = (unsigned short*)(ws + 118 * MBYTE);
    unsigned short* w1T     = (unsigned short*)(ws + 120 * MBYTE);
    unsigned short* w2T     = (unsigned short*)(ws + 128 * MBYTE);
    unsigned short* g_buf   = (unsigned short*)(ws + 16 * MBYTE);

    const int M = 8192;

    convT_kernel<<<dim3(3072 / 32, 1024 / 32), 256, 0, stream>>>(qkv_w, wqT, 1024, 3072);
    convT_kernel<<<dim3(1024 / 32, 1024 / 32), 256, 0, stream>>>(proj_w, wpT, 1024, 1024);
    convT_kernel<<<dim3(4096 / 32, 1024 / 32), 256, 0, stream>>>(fc1_w, w1T, 1024, 4096);
    convT_kernel<<<dim3(1024 / 32, 4096 / 32), 256, 0, stream>>>(fc2_w, w2T, 4096, 1024);

    ln_kernel<<<M, 256, 0, stream>>>(x, h_buf);

    // qkv: 8192x3072, K=1024  (BN=128, grid 24x32 = 768 = 3.0 even rounds)
    gemm8p<0, 128><<<dim3(3072 / 128, M / 256), 512, 0, stream>>>(
        h_buf, wqT, qkv_b, nullptr, nullptr, qkv_buf, M, 3072, 1024);

    vT_kernel<<<dim3(64, 2, 64), 256, 0, stream>>>(qkv_buf, vT_buf);

    attn_kernel<<<dim3(32 * 64), 256, 0, stream>>>(qkv_buf, vT_buf, o_buf);

    // proj: 8192x1024, K=1024  (BN=128, grid 8x32 = 256 = full machine)
    gemm8p<2, 128><<<dim3(1024 / 128, M / 256), 512, 0, stream>>>(
        o_buf, wpT, proj_b, x, x2_buf, nullptr, M, 1024, 1024);

    ln_kernel<<<M, 256, 0, stream>>>(x2_buf, h_buf);

    // fc1: 8192x4096, K=1024  (BN=128, grid 32x32 = 1024 = 4.0 even rounds)
    gemm8p<1, 128><<<dim3(4096 / 128, M / 256), 512, 0, stream>>>(
        h_buf, w1T, fc1_b, nullptr, nullptr, g_buf, M, 4096, 1024);

    // fc2: 8192x1024, K=4096  (BN=128, grid 8x32 = 256 = full machine)
    gemm8p<2, 128><<<dim3(1024 / 128, M / 256), 512, 0, stream>>>(
        g_buf, w2T, fc2_b, x2_buf, out, nullptr, M, 1024, 4096);
}

// Round 19
// 401.399 us; speedup vs baseline: 1.0774x; 1.0774x over previous
//
#include <hip/hip_runtime.h>
#include <hip/hip_bf16.h>

typedef float f32x4 __attribute__((ext_vector_type(4)));
typedef __bf16 bf16x8 __attribute__((ext_vector_type(8)));
typedef unsigned short us8 __attribute__((ext_vector_type(8)));

#define MBYTE (1ull << 20)

#define QSCALE_LOG2E 0.18033688011112042f
#define GELU_K 2.3022081902f

__device__ __forceinline__ unsigned short f2bf(float f) {
    __bf16 h = (__bf16)f;
    return __builtin_bit_cast(unsigned short, h);
}

__device__ __forceinline__ float fast_exp2(float x) {
    return __builtin_amdgcn_exp2f(x);
}

__device__ __forceinline__ f32x4 mfma16(bf16x8 a, bf16x8 b, f32x4 c) {
    return __builtin_amdgcn_mfma_f32_16x16x32_bf16(a, b, c, 0, 0, 0);
}

__device__ __forceinline__ void gload16(const void* g, void* l) {
    __builtin_amdgcn_global_load_lds(
        (const __attribute__((address_space(1))) unsigned int*)g,
        (__attribute__((address_space(3))) unsigned int*)l, 16, 0, 0);
}

// ---------------- LayerNorm: fp32 [rows][1024] -> bf16 ----------------
__global__ __launch_bounds__(256) void ln_kernel(const float* __restrict__ x,
                                                 unsigned short* __restrict__ out) {
    int row = blockIdx.x;
    int t = threadIdx.x;
    const float* xr = x + (size_t)row * 1024;
    float4 v = *(const float4*)(xr + t * 4);
    float s = v.x + v.y + v.z + v.w;
    float ss = v.x * v.x + v.y * v.y + v.z * v.z + v.w * v.w;
    #pragma unroll
    for (int off = 1; off < 64; off <<= 1) {
        s += __shfl_xor(s, off);
        ss += __shfl_xor(ss, off);
    }
    __shared__ float ps[4], pss[4];
    int wid = t >> 6, lane = t & 63;
    if (lane == 0) { ps[wid] = s; pss[wid] = ss; }
    __syncthreads();
    s = ps[0] + ps[1] + ps[2] + ps[3];
    ss = pss[0] + pss[1] + pss[2] + pss[3];
    float mean = s * (1.0f / 1024.0f);
    float var = ss * (1.0f / 1024.0f) - mean * mean;
    float rs = rsqrtf(var + 1e-6f);
    ushort4 ov;
    ov.x = f2bf((v.x - mean) * rs);
    ov.y = f2bf((v.y - mean) * rs);
    ov.z = f2bf((v.z - mean) * rs);
    ov.w = f2bf((v.w - mean) * rs);
    *(ushort4*)(out + (size_t)row * 1024 + t * 4) = ov;
}

// ------------- transpose + fp32->bf16: W[K][N] -> Wt[N][K] -------------
__global__ __launch_bounds__(256) void convT_kernel(const float* __restrict__ W,
                                                    unsigned short* __restrict__ Wt,
                                                    int K, int N) {
    __shared__ float tile[32][33];
    int t = threadIdx.x;
    int tx = t & 31, ty = t >> 5;
    int bx = blockIdx.x, by = blockIdx.y;
    #pragma unroll
    for (int r = 0; r < 4; r++) {
        int row = by * 32 + ty + r * 8;
        int col = bx * 32 + tx;
        tile[ty + r * 8][tx] = W[(size_t)row * N + col];
    }
    __syncthreads();
    #pragma unroll
    for (int r = 0; r < 4; r++) {
        int orow = bx * 32 + ty + r * 8;
        int ocol = by * 32 + tx;
        Wt[(size_t)orow * K + ocol] = f2bf(tile[tx][ty + r * 8]);
    }
}

// ------------- V transpose: qkv V-part bf16 -> vT[bh][64][2048] -------------
__global__ __launch_bounds__(256) void vT_kernel(const unsigned short* __restrict__ qkv,
                                                 unsigned short* __restrict__ vT) {
    __shared__ unsigned short tile[32][34];
    int t = threadIdx.x;
    int tx = t & 31, ty = t >> 5;
    int lt = blockIdx.x, dt = blockIdx.y, bh = blockIdx.z;
    int b = bh >> 4, h = bh & 15;
    const unsigned short* src = qkv + (size_t)(b * 2048 + lt * 32) * 3072 + 2048 + h * 64 + dt * 32;
    #pragma unroll
    for (int r = 0; r < 4; r++)
        tile[ty + r * 8][tx] = src[(size_t)(ty + r * 8) * 3072 + tx];
    __syncthreads();
    int perm = (lt & 1) * 32 + ((tx >> 2) & 3) * 8 + ((tx >> 4) & 1) * 4 + (tx & 3);
    unsigned short* dst = vT + ((size_t)bh * 64 + dt * 32) * 2048 + (size_t)(lt >> 1) * 64;
    #pragma unroll
    for (int r = 0; r < 4; r++)
        dst[(size_t)(ty + r * 8) * 2048 + perm] = tile[tx][ty + r * 8];
}

// ------- GEMM v9 (R17-proven): 256xBN tile, BK=64, 8 waves, 4-phase quadrant
// schedule, counted end-of-tile vmcnt, region-safe late staging. ------
template <int EPI, int BN>
__global__ __launch_bounds__(512, 2) void gemm8p(const unsigned short* __restrict__ A,
                                                 const unsigned short* __restrict__ Bt,
                                                 const float* __restrict__ bias,
                                                 const float* __restrict__ res,
                                                 float* __restrict__ outF,
                                                 unsigned short* __restrict__ outB,
                                                 int M, int N, int K) {
    constexpr int NREP = BN / 64;
    constexpr int NH = NREP / 2;
    constexpr int BHROWS = BN / 2;
    constexpr int WCOLS = BN / 4;

    __shared__ __align__(16) unsigned short As[2][2][128 * 64];
    __shared__ __align__(16) unsigned short Bs[2][2][BHROWS * 64];

    int t = threadIdx.x;
    int lane = t & 63, wid = t >> 6;
    int ql = lane & 15, hi = lane >> 4;

    // XCD-aware bijective swizzle (grids: 768/256/512/256, all %8==0)
    int gx = gridDim.x;
    int nwg = gx * gridDim.y;
    int orig = blockIdx.y * gx + blockIdx.x;
    int cpx = nwg >> 3;
    int swz = (orig & 7) * cpx + (orig >> 3);
    int bm = swz / gx, bn = swz % gx;

    int wm = wid >> 2, wn = wid & 3;
    f32x4 acc[8][NREP] = {};

    int lrow = lane >> 3;
    int schunk = ((lane & 7) ^ lrow) * 8;
    const unsigned short* gA = A + (size_t)(bm * 256 + wid * 8 + lrow) * K + schunk;
    const unsigned short* gB = Bt + (size_t)(bn * BN + wid * 8 + lrow) * K + schunk;

    auto SA = [&](int d, int hh, int kt) {
        size_t ko = (size_t)kt * 64;
        gload16(gA + (size_t)(hh * 128) * K + ko, &As[d][hh][(wid * 8) * 64]);
        gload16(gA + (size_t)(hh * 128 + 64) * K + ko, &As[d][hh][(64 + wid * 8) * 64]);
    };
    auto SB = [&](int d, int hh, int kt) {
        size_t ko = (size_t)kt * 64;
        gload16(gB + (size_t)(hh * BHROWS) * K + ko, &Bs[d][hh][(wid * 8) * 64]);
        if constexpr (BN == 256)
            gload16(gB + (size_t)(hh * BHROWS + 64) * K + ko, &Bs[d][hh][(64 + wid * 8) * 64]);
    };

    int rsl0 = ((0 + hi) ^ (ql & 7)) * 8;
    int rsl1 = ((4 + hi) ^ (ql & 7)) * 8;

    const int NT = K >> 6;
    int bh_ = (WCOLS * wn) / BHROWS;
    int brow = (WCOLS * wn) % BHROWS;

    auto GATE_N = [&]() {
        if constexpr (BN == 256) asm volatile("s_waitcnt vmcnt(8)" ::: "memory");
        else                     asm volatile("s_waitcnt vmcnt(6)" ::: "memory");
    };

    SA(0, 0, 0); SA(0, 1, 0); SB(0, 0, 0); SB(0, 1, 0);
    __builtin_amdgcn_sched_barrier(0);
    SA(1, 0, 1); SA(1, 1, 1); SB(1, 0, 1); SB(1, 1, 1);
    GATE_N();
    __builtin_amdgcn_sched_barrier(0);
    __builtin_amdgcn_s_barrier();

    for (int kt = 0; kt < NT; ++kt) {
        int d = kt & 1;
        bool st = (kt + 2 < NT);
        const unsigned short* Ah = &As[d][wm][0];
        const unsigned short* Bh = &Bs[d][bh_][0];

        bf16x8 af[4][2], bfa[NH][2], bfb[NH][2];

        // ---- ph0: read A(mh0) + B(nh0); MFMA quadrant (0,0) ----
        #pragma unroll
        for (int m = 0; m < 4; m++) {
            af[m][0] = *(const bf16x8*)&Ah[(m * 16 + ql) * 64 + rsl0];
            af[m][1] = *(const bf16x8*)&Ah[(m * 16 + ql) * 64 + rsl1];
        }
        #pragma unroll
        for (int n = 0; n < NH; n++) {
            bfa[n][0] = *(const bf16x8*)&Bh[(brow + n * 16 + ql) * 64 + rsl0];
            bfa[n][1] = *(const bf16x8*)&Bh[(brow + n * 16 + ql) * 64 + rsl1];
        }
        __builtin_amdgcn_s_setprio(1);
        #pragma unroll
        for (int m = 0; m < 4; m++)
            #pragma unroll
            for (int n = 0; n < NH; n++) {
                acc[m][n] = mfma16(af[m][0], bfa[n][0], acc[m][n]);
                acc[m][n] = mfma16(af[m][1], bfa[n][1], acc[m][n]);
            }
        __builtin_amdgcn_s_setprio(0);

        // ---- ph1: read B(nh1); MFMA quadrant (0,1) ----
        #pragma unroll
        for (int n = 0; n < NH; n++) {
            bfb[n][0] = *(const bf16x8*)&Bh[(brow + NH * 16 + n * 16 + ql) * 64 + rsl0];
            bfb[n][1] = *(const bf16x8*)&Bh[(brow + NH * 16 + n * 16 + ql) * 64 + rsl1];
        }
        __builtin_amdgcn_s_setprio(1);
        #pragma unroll
        for (int m = 0; m < 4; m++)
            #pragma unroll
            for (int n = 0; n < NH; n++) {
                acc[m][NH + n] = mfma16(af[m][0], bfb[n][0], acc[m][NH + n]);
                acc[m][NH + n] = mfma16(af[m][1], bfb[n][1], acc[m][NH + n]);
            }
        __builtin_amdgcn_s_setprio(0);

        // fence1: all waves' B reads complete -> safe to overwrite B regions
        if (st) {
            asm volatile("s_waitcnt lgkmcnt(0)" ::: "memory");
            __builtin_amdgcn_sched_barrier(0);
            __builtin_amdgcn_s_barrier();
        }

        // ---- ph2: stage B(t+2); read A(mh1); MFMA quadrant (1,0) ----
        if (st) { SB(d, 0, kt + 2); SB(d, 1, kt + 2); }
        #pragma unroll
        for (int m = 0; m < 4; m++) {
            af[m][0] = *(const bf16x8*)&Ah[(64 + m * 16 + ql) * 64 + rsl0];
            af[m][1] = *(const bf16x8*)&Ah[(64 + m * 16 + ql) * 64 + rsl1];
        }
        __builtin_amdgcn_s_setprio(1);
        #pragma unroll
        for (int m = 0; m < 4; m++)
            #pragma unroll
            for (int n = 0; n < NH; n++) {
                acc[4 + m][n] = mfma16(af[m][0], bfa[n][0], acc[4 + m][n]);
                acc[4 + m][n] = mfma16(af[m][1], bfa[n][1], acc[4 + m][n]);
            }
        __builtin_amdgcn_s_setprio(0);

        // fence2: all waves' A reads complete -> safe to overwrite A regions
        if (st) {
            asm volatile("s_waitcnt lgkmcnt(0)" ::: "memory");
            __builtin_amdgcn_sched_barrier(0);
            __builtin_amdgcn_s_barrier();
        }

        // ---- ph3: stage A(t+2); MFMA quadrant (1,1) ----
        if (st) { SA(d, 0, kt + 2); SA(d, 1, kt + 2); }
        __builtin_amdgcn_s_setprio(1);
        #pragma unroll
        for (int m = 0; m < 4; m++)
            #pragma unroll
            for (int n = 0; n < NH; n++) {
                acc[4 + m][NH + n] = mfma16(af[m][0], bfb[n][0], acc[4 + m][NH + n]);
                acc[4 + m][NH + n] = mfma16(af[m][1], bfb[n][1], acc[4 + m][NH + n]);
            }
        __builtin_amdgcn_s_setprio(0);

        // end gate: force tile t+1's loads; tile t+2's stay in flight
        if (st) GATE_N();
        else    asm volatile("s_waitcnt vmcnt(0)" ::: "memory");
        __builtin_amdgcn_sched_barrier(0);
        __builtin_amdgcn_s_barrier();
    }

    #pragma unroll
    for (int m = 0; m < 8; m++) {
        #pragma unroll
        for (int n = 0; n < NREP; n++) {
            int col = bn * BN + wn * WCOLS + n * 16 + ql;
            float bv = bias[col];
            #pragma unroll
            for (int r = 0; r < 4; r++) {
                int row = bm * 256 + wm * 128 + m * 16 + hi * 4 + r;
                float val = acc[m][n][r] + bv;
                if (EPI == 0) {
                    if (col < 1024) val *= QSCALE_LOG2E;
                    outB[(size_t)row * N + col] = f2bf(val);
                } else if (EPI == 1) {
                    float w = val + 0.044715f * val * val * val;
                    float g = val / (1.0f + fast_exp2(-GELU_K * w));
                    outB[(size_t)row * N + col] = f2bf(g);
                } else {
                    outF[(size_t)row * N + col] = val + res[(size_t)row * N + col];
                }
            }
        }
    }
}

// --- Flash attention v9 (R14-proven): swapped QK^T, in-register P, no max
//     tracking, lsum via ones-MFMA, dbuf stage-before-compute, 1 barrier/tile ---
__global__ __launch_bounds__(256) void attn_kernel(const unsigned short* __restrict__ qkv,
                                                   const unsigned short* __restrict__ vT,
                                                   unsigned short* __restrict__ o) {
    int bid = blockIdx.x;
    int qb = bid & 31;
    int bh = bid >> 5;
    int b = bh >> 4, h = bh & 15;
    int t = threadIdx.x, lane = t & 63, wid = t >> 6;

    const unsigned short* base = qkv + (size_t)b * 2048 * 3072 + h * 64;
    const unsigned short* vbase = vT + (size_t)bh * 64 * 2048;

    __shared__ __align__(16) unsigned short Ks[2][2][64][32];
    __shared__ __align__(16) unsigned short Vs[2][2][64][32];

    int ql = lane & 15;
    int hi = lane >> 4;

    bf16x8 qf[2];
    {
        int qrow = qb * 64 + wid * 16 + ql;
        const unsigned short* qp = base + (size_t)qrow * 3072 + hi * 8;
        qf[0] = *(const bf16x8*)(qp);
        qf[1] = *(const bf16x8*)(qp + 32);
    }

    us8 ones_u;
    #pragma unroll
    for (int j = 0; j < 8; j++) ones_u[j] = 0x3F80;
    bf16x8 ones = __builtin_bit_cast(bf16x8, ones_u);

    f32x4 accO[4] = {};
    f32x4 lacc = {};

    int srow = wid * 16 + (lane >> 2);
    int schunk = ((lane & 3) ^ ((lane >> 3) & 3)) * 8;
    const unsigned short* gk = base + 1024 + (size_t)srow * 3072 + schunk;
    const unsigned short* gv = vbase + (size_t)srow * 2048 + schunk;

    auto STAGE = [&](int buf, int kt) {
        const unsigned short* pk = gk + (size_t)kt * 64 * 3072;
        const unsigned short* pv = gv + (size_t)kt * 64;
        gload16(pk, &Ks[buf][0][wid * 16][0]);
        gload16(pk + 32, &Ks[buf][1][wid * 16][0]);
        gload16(pv, &Vs[buf][0][wid * 16][0]);
        gload16(pv + 32, &Vs[buf][1][wid * 16][0]);
    };

    int rchunk = (hi ^ ((ql >> 1) & 3)) * 8;

    STAGE(0, 0);
    asm volatile("s_waitcnt vmcnt(0)" ::: "memory");
    __builtin_amdgcn_sched_barrier(0);
    __builtin_amdgcn_s_barrier();

    int buf = 0;
    for (int kt = 0; kt < 32; kt++) {
        if (kt + 1 < 32) STAGE(buf ^ 1, kt + 1);

        f32x4 s0 = {}, s1 = {}, s2 = {}, s3 = {};
        #pragma unroll
        for (int c = 0; c < 2; c++) {
            bf16x8 a0 = *(const bf16x8*)&Ks[buf][c][ 0 + ql][rchunk];
            bf16x8 a1 = *(const bf16x8*)&Ks[buf][c][16 + ql][rchunk];
            bf16x8 a2 = *(const bf16x8*)&Ks[buf][c][32 + ql][rchunk];
            bf16x8 a3 = *(const bf16x8*)&Ks[buf][c][48 + ql][rchunk];
            s0 = mfma16(a0, qf[c], s0);
            s1 = mfma16(a1, qf[c], s1);
            s2 = mfma16(a2, qf[c], s2);
            s3 = mfma16(a3, qf[c], s3);
        }

        us8 pu0, pu1;
        #pragma unroll
        for (int j = 0; j < 4; j++) {
            pu0[j]     = f2bf(fast_exp2(s0[j]));
            pu0[4 + j] = f2bf(fast_exp2(s1[j]));
            pu1[j]     = f2bf(fast_exp2(s2[j]));
            pu1[4 + j] = f2bf(fast_exp2(s3[j]));
        }
        bf16x8 paf0 = __builtin_bit_cast(bf16x8, pu0);
        bf16x8 paf1 = __builtin_bit_cast(bf16x8, pu1);

        #pragma unroll
        for (int nn = 0; nn < 4; nn++) {
            bf16x8 bv0 = *(const bf16x8*)&Vs[buf][0][nn * 16 + ql][rchunk];
            bf16x8 bv1 = *(const bf16x8*)&Vs[buf][1][nn * 16 + ql][rchunk];
            accO[nn] = mfma16(paf0, bv0, accO[nn]);
            accO[nn] = mfma16(paf1, bv1, accO[nn]);
        }
        lacc = mfma16(paf0, ones, lacc);
        lacc = mfma16(paf1, ones, lacc);

        asm volatile("s_waitcnt vmcnt(0)" ::: "memory");
        __builtin_amdgcn_sched_barrier(0);
        __builtin_amdgcn_s_barrier();
        buf ^= 1;
    }

    #pragma unroll
    for (int r = 0; r < 4; r++) {
        float rq = 1.0f / lacc[r];
        int row = qb * 64 + wid * 16 + hi * 4 + r;
        #pragma unroll
        for (int nn = 0; nn < 4; nn++) {
            int col = h * 64 + nn * 16 + ql;
            o[(size_t)(b * 2048 + row) * 1024 + col] = f2bf(accO[nn][r] * rq);
        }
    }
}

extern "C" void kernel_launch(void* const* d_in, const int* in_sizes, int n_in,
                              void* d_out, int out_size, void* d_ws, size_t ws_size,
                              hipStream_t stream) {
    const float* x      = (const float*)d_in[0];
    const float* qkv_w  = (const float*)d_in[1];
    const float* qkv_b  = (const float*)d_in[2];
    const float* proj_w = (const float*)d_in[3];
    const float* proj_b = (const float*)d_in[4];
    const float* fc1_w  = (const float*)d_in[5];
    const float* fc1_b  = (const float*)d_in[6];
    const float* fc2_w  = (const float*)d_in[7];
    const float* fc2_b  = (const float*)d_in[8];
    float* out = (float*)d_out;

    char* ws = (char*)d_ws;
    unsigned short* h_buf   = (unsigned short*)(ws + 0 * MBYTE);
    unsigned short* qkv_buf = (unsigned short*)(ws + 16 * MBYTE);
    unsigned short* o_buf   = (unsigned short*)(ws + 64 * MBYTE);
    float*          x2_buf  = (float*)(ws + 80 * MBYTE);
    unsigned short* vT_buf  = (unsigned short*)(ws + 80 * MBYTE);
    unsigned short* wqT     = (unsigned short*)(ws + 112 * MBYTE);
    unsigned short* wpT     = (unsigned short*)(ws + 118 * MBYTE);
    unsigned short* w1T     = (unsigned short*)(ws + 120 * MBYTE);
    unsigned short* w2T     = (unsigned short*)(ws + 128 * MBYTE);
    unsigned short* g_buf   = (unsigned short*)(ws + 16 * MBYTE);

    const int M = 8192;

    convT_kernel<<<dim3(3072 / 32, 1024 / 32), 256, 0, stream>>>(qkv_w, wqT, 1024, 3072);
    convT_kernel<<<dim3(1024 / 32, 1024 / 32), 256, 0, stream>>>(proj_w, wpT, 1024, 1024);
    convT_kernel<<<dim3(4096 / 32, 1024 / 32), 256, 0, stream>>>(fc1_w, w1T, 1024, 4096);
    convT_kernel<<<dim3(1024 / 32, 4096 / 32), 256, 0, stream>>>(fc2_w, w2T, 4096, 1024);

    ln_kernel<<<M, 256, 0, stream>>>(x, h_buf);

    // qkv: 8192x3072, K=1024  (BN=128, grid 24x32 = 768 = 3.0 even rounds)
    gemm8p<0, 128><<<dim3(3072 / 128, M / 256), 512, 0, stream>>>(
        h_buf, wqT, qkv_b, nullptr, nullptr, qkv_buf, M, 3072, 1024);

    vT_kernel<<<dim3(64, 2, 64), 256, 0, stream>>>(qkv_buf, vT_buf);

    attn_kernel<<<dim3(32 * 64), 256, 0, stream>>>(qkv_buf, vT_buf, o_buf);

    // proj: 8192x1024, K=1024  (BN=128, grid 8x32 = 256 = full machine)
    gemm8p<2, 128><<<dim3(1024 / 128, M / 256), 512, 0, stream>>>(
        o_buf, wpT, proj_b, x, x2_buf, nullptr, M, 1024, 1024);

    ln_kernel<<<M, 256, 0, stream>>>(x2_buf, h_buf);

    // fc1: 8192x4096, K=1024  (BN=256, grid 16x32 = 512 = 2.0 even rounds)
    gemm8p<1, 256><<<dim3(4096 / 256, M / 256), 512, 0, stream>>>(
        h_buf, w1T, fc1_b, nullptr, nullptr, g_buf, M, 4096, 1024);

    // fc2: 8192x1024, K=4096  (BN=128, grid 8x32 = 256 = full machine)
    gemm8p<2, 128><<<dim3(1024 / 128, M / 256), 512, 0, stream>>>(
        g_buf, w2T, fc2_b, x2_buf, out, nullptr, M, 1024, 4096);
}